// Round 1
// baseline (586.321 us; speedup 1.0000x reference)
//
#include <hip/hip_runtime.h>
#include <hip/hip_bf16.h>
#include <math.h>

// ---------------------------------------------------------------------------
// HADCommNetwork forward, fp32 baseline.
// B=64, N=512, OBS=128, H=256, M=128, ACT=16, T=B*N=32768
//
// Pipeline:
//   build_wm: pack Wc|Wn|Wb -> Wm[256][128], bc|bn|bb -> bm[128]
//   enc  = relu(obs @ We + be)                 [T x 256]
//   msg  = enc @ Wm + bm                       [T x 128]
//   imp  = sigmoid(enc . Wi + bi); nrm = ||obs||   [T]
//   q    = enc @ Wq + bq                       [T x 128]
//   k    = msg @ Wk + bk                       [T x 128]
//   v    = msg @ Wv + bv                       [T x 128]
//   per chunk of batches:
//     S[b,q,k] = (q.k)*rsqrtD*imp_q*imp_k + 0.5*(obs.obs)/((nq+e)(nk+e))
//                (virtual K=256 NT GEMM, scales applied on LDS load)
//     softmax rows
//     agg = S @ v     (batched NN GEMM, 64x64 tiles)
//   x    = relu([enc|agg] @ Wp + bp)           [T x 256] (two-source GEMM)
//   logits = x @ Wa + ba  -> d_out[0 : 524288]
//   value  = x @ Wcr + bcr -> d_out[524288 : 557056]
//
// Workspace (floats): enc 8388608 | msg/agg 4194304 | q 4194304 | k 4194304 |
//   v 4194304 | imp 32768 | nrm 32768 | Wm 32768 | bm 128 | scores chunk*262144
// x aliases q+k (dead after scores). Total @chunk=16: ~118 MB.
// ---------------------------------------------------------------------------

#define RSQRT_D 0.08838834764831843f  // 1/sqrt(128)

// ---------------- pack message weights ----------------
__global__ __launch_bounds__(256) void build_wm(
    const float* __restrict__ Wc, const float* __restrict__ Wn,
    const float* __restrict__ Wb, const float* __restrict__ bc,
    const float* __restrict__ bn, const float* __restrict__ bb,
    float* __restrict__ Wm, float* __restrict__ bm) {
  int idx = blockIdx.x * 256 + threadIdx.x;  // over 256*128
  int h = idx >> 7, d = idx & 127;
  float v;
  if (d < 32)      v = Wc[h * 32 + d];
  else if (d < 96) v = Wn[h * 64 + (d - 32)];
  else             v = Wb[h * 32 + (d - 96)];
  Wm[idx] = v;
  if (idx < 128) {
    float bv = (idx < 32) ? bc[idx] : (idx < 96) ? bn[idx - 32] : bb[idx - 96];
    bm[idx] = bv;
  }
}

// ---------------- generic NN GEMM ----------------
// C = ACT( [A1|A2] @ W + bias ), 256 threads, BK=8, microtile TM x TN.
// TM/TN==8 -> split micro-groups at +0 / +64 (keeps LDS reads <=2-way).
// blockIdx.z batching via strideA (A1), strideW, strideC.
template <int ACT, int BM, int BN, int TM, int TN>
__global__ __launch_bounds__(256, 2) void gemm_nn(
    const float* __restrict__ A1, int lda1, int K1,
    const float* __restrict__ A2, int lda2, int Ktot,
    const float* __restrict__ W, int ldw,
    const float* __restrict__ bias,
    float* __restrict__ C, int ldc,
    long strideA, long strideW, long strideC) {
  __shared__ float As[8][BM];
  __shared__ float Ws[8][BN];
  const int tid = threadIdx.x;
  const int tx = tid & 15, ty = tid >> 4;
  const float* A1z = A1 + (long)blockIdx.z * strideA;
  const float* Wz = W + (long)blockIdx.z * strideW;
  float* Cz = C + (long)blockIdx.z * strideC;
  const int bm = blockIdx.y * BM, bn = blockIdx.x * BN;

  float acc[TM][TN];
#pragma unroll
  for (int i = 0; i < TM; ++i)
#pragma unroll
    for (int j = 0; j < TN; ++j) acc[i][j] = 0.f;

  for (int kt = 0; kt < Ktot; kt += 8) {
    const float* Asrc;
    int lda, kloc;
    if (kt < K1) { Asrc = A1z; lda = lda1; kloc = kt; }
    else         { Asrc = A2;  lda = lda2; kloc = kt - K1; }
    // A tile: BM x 8 -> As[k][m] (transposed)
    constexpr int AITER = (BM * 2 + 255) / 256;
#pragma unroll
    for (int ii = 0; ii < AITER; ++ii) {
      int i = tid + ii * 256;
      if ((BM * 2) % 256 == 0 || i < BM * 2) {
        int r = i >> 1, k4 = (i & 1) * 4;
        float4 v = *(const float4*)(Asrc + (size_t)(bm + r) * lda + kloc + k4);
        As[k4 + 0][r] = v.x; As[k4 + 1][r] = v.y;
        As[k4 + 2][r] = v.z; As[k4 + 3][r] = v.w;
      }
    }
    // W tile: 8 x BN
    constexpr int WITER = (BN * 2 + 255) / 256;
#pragma unroll
    for (int ii = 0; ii < WITER; ++ii) {
      int i = tid + ii * 256;
      if ((BN * 2) % 256 == 0 || i < BN * 2) {
        int kr = i / (BN / 4);
        int c4 = (i % (BN / 4)) * 4;
        *(float4*)&Ws[kr][c4] =
            *(const float4*)(Wz + (size_t)(kt + kr) * ldw + bn + c4);
      }
    }
    __syncthreads();
#pragma unroll
    for (int kk = 0; kk < 8; ++kk) {
      float ar[TM], br[TN];
      {
        float4 t0 = *(const float4*)&As[kk][ty * 4];
        ar[0] = t0.x; ar[1] = t0.y; ar[2] = t0.z; ar[3] = t0.w;
      }
      if constexpr (TM == 8) {
        float4 t1 = *(const float4*)&As[kk][64 + ty * 4];
        ar[4] = t1.x; ar[5] = t1.y; ar[6] = t1.z; ar[7] = t1.w;
      }
      {
        float4 t0 = *(const float4*)&Ws[kk][tx * 4];
        br[0] = t0.x; br[1] = t0.y; br[2] = t0.z; br[3] = t0.w;
      }
      if constexpr (TN == 8) {
        float4 t1 = *(const float4*)&Ws[kk][64 + tx * 4];
        br[4] = t1.x; br[5] = t1.y; br[6] = t1.z; br[7] = t1.w;
      }
#pragma unroll
      for (int i = 0; i < TM; ++i)
#pragma unroll
        for (int j = 0; j < TN; ++j) acc[i][j] = fmaf(ar[i], br[j], acc[i][j]);
    }
    __syncthreads();
  }
  // epilogue
#pragma unroll
  for (int i = 0; i < TM; ++i) {
    int r = bm + ((TM == 8 && i >= 4) ? (64 + ty * 4 + (i - 4)) : (ty * 4 + i));
#pragma unroll
    for (int cg = 0; cg < TN / 4; ++cg) {
      int c = bn + cg * 64 + tx * 4;
      float4 bv;
      if (bias) bv = *(const float4*)(bias + c);
      else      bv = make_float4(0.f, 0.f, 0.f, 0.f);
      float4 o;
      o.x = acc[i][cg * 4 + 0] + bv.x;
      o.y = acc[i][cg * 4 + 1] + bv.y;
      o.z = acc[i][cg * 4 + 2] + bv.z;
      o.w = acc[i][cg * 4 + 3] + bv.w;
      if (ACT == 1) {
        o.x = fmaxf(o.x, 0.f); o.y = fmaxf(o.y, 0.f);
        o.z = fmaxf(o.z, 0.f); o.w = fmaxf(o.w, 0.f);
      }
      *(float4*)(Cz + (size_t)r * ldc + c) = o;
    }
  }
}

// ---------------- importance + norms ----------------
__global__ __launch_bounds__(256) void imp_nrm_kernel(
    const float* __restrict__ enc, const float* __restrict__ obs,
    const float* __restrict__ Wi, const float* __restrict__ bi,
    float* __restrict__ imp, float* __restrict__ nrm) {
  int t = blockIdx.x * 4 + (threadIdx.x >> 6);
  int lane = threadIdx.x & 63;
  float4 e = *(const float4*)(enc + (size_t)t * 256 + lane * 4);
  float4 w = *(const float4*)(Wi + lane * 4);
  float s1 = e.x * w.x + e.y * w.y + e.z * w.z + e.w * w.w;
  float2 o = *(const float2*)(obs + (size_t)t * 128 + lane * 2);
  float s2 = o.x * o.x + o.y * o.y;
#pragma unroll
  for (int off = 1; off < 64; off <<= 1) {
    s1 += __shfl_xor(s1, off);
    s2 += __shfl_xor(s2, off);
  }
  if (lane == 0) {
    imp[t] = 1.0f / (1.0f + __expf(-(s1 + bi[0])));
    nrm[t] = sqrtf(s2);
  }
}

// ---------------- scores: virtual-K=256 NT GEMM ----------------
// S[z][q][k] = sum_d A[q][d]*B[k][d], where for d<128 A=Q*imp_q*rsqrtD, B=K*imp_k
// and for d>=128 A=0.5*obs/(nq+e), B=obs/(nk+e).
__global__ __launch_bounds__(256, 2) void scores_nt(
    const float* __restrict__ Qb, const float* __restrict__ Kb,
    const float* __restrict__ obs, const float* __restrict__ imp,
    const float* __restrict__ nrm, float* __restrict__ S, int c0) {
  __shared__ float As[8][128];
  __shared__ float Bs[8][128];
  __shared__ float sQA[128], sOA[128], sQB[128], sOB[128];
  const int tid = threadIdx.x;
  const int tx = tid & 15, ty = tid >> 4;
  const int b = c0 + blockIdx.z;
  const int bm = blockIdx.y * 128, bn = blockIdx.x * 128;
  const size_t tokA = (size_t)b * 512 + bm;
  const size_t tokB = (size_t)b * 512 + bn;
  if (tid < 128) {
    sQA[tid] = imp[tokA + tid] * RSQRT_D;
    sOA[tid] = 0.5f / (nrm[tokA + tid] + 1e-8f);
    sQB[tid] = imp[tokB + tid];
    sOB[tid] = 1.0f / (nrm[tokB + tid] + 1e-8f);
  }
  __syncthreads();

  float acc[8][8];
#pragma unroll
  for (int i = 0; i < 8; ++i)
#pragma unroll
    for (int j = 0; j < 8; ++j) acc[i][j] = 0.f;

  const int lr = tid >> 1;
  const int lk = (tid & 1) * 4;
  for (int kt = 0; kt < 256; kt += 8) {
    bool qpart = kt < 128;
    {
      const float* src = qpart ? (Qb + (tokA + lr) * 128 + kt + lk)
                               : (obs + (tokA + lr) * 128 + (kt - 128) + lk);
      float sc = qpart ? sQA[lr] : sOA[lr];
      float4 v = *(const float4*)src;
      As[lk + 0][lr] = v.x * sc; As[lk + 1][lr] = v.y * sc;
      As[lk + 2][lr] = v.z * sc; As[lk + 3][lr] = v.w * sc;
      const float* srcB = qpart ? (Kb + (tokB + lr) * 128 + kt + lk)
                                : (obs + (tokB + lr) * 128 + (kt - 128) + lk);
      float scB = qpart ? sQB[lr] : sOB[lr];
      float4 w = *(const float4*)srcB;
      Bs[lk + 0][lr] = w.x * scB; Bs[lk + 1][lr] = w.y * scB;
      Bs[lk + 2][lr] = w.z * scB; Bs[lk + 3][lr] = w.w * scB;
    }
    __syncthreads();
#pragma unroll
    for (int kk = 0; kk < 8; ++kk) {
      float ar[8], br[8];
      float4 a0 = *(const float4*)&As[kk][ty * 4];
      float4 a1 = *(const float4*)&As[kk][64 + ty * 4];
      ar[0] = a0.x; ar[1] = a0.y; ar[2] = a0.z; ar[3] = a0.w;
      ar[4] = a1.x; ar[5] = a1.y; ar[6] = a1.z; ar[7] = a1.w;
      float4 b0 = *(const float4*)&Bs[kk][tx * 4];
      float4 b1 = *(const float4*)&Bs[kk][64 + tx * 4];
      br[0] = b0.x; br[1] = b0.y; br[2] = b0.z; br[3] = b0.w;
      br[4] = b1.x; br[5] = b1.y; br[6] = b1.z; br[7] = b1.w;
#pragma unroll
      for (int i = 0; i < 8; ++i)
#pragma unroll
        for (int j = 0; j < 8; ++j) acc[i][j] = fmaf(ar[i], br[j], acc[i][j]);
    }
    __syncthreads();
  }
  float* Sb = S + (size_t)blockIdx.z * 512 * 512;
#pragma unroll
  for (int i = 0; i < 8; ++i) {
    int r = bm + ((i >= 4) ? (64 + ty * 4 + (i - 4)) : (ty * 4 + i));
    float4 o0 = make_float4(acc[i][0], acc[i][1], acc[i][2], acc[i][3]);
    float4 o1 = make_float4(acc[i][4], acc[i][5], acc[i][6], acc[i][7]);
    *(float4*)(Sb + (size_t)r * 512 + bn + tx * 4) = o0;
    *(float4*)(Sb + (size_t)r * 512 + bn + 64 + tx * 4) = o1;
  }
}

// ---------------- row softmax (512 wide), wave per row ----------------
__global__ __launch_bounds__(256) void softmax_rows(float* __restrict__ S) {
  int r = blockIdx.x * 4 + (threadIdx.x >> 6);
  int lane = threadIdx.x & 63;
  float* row = S + (size_t)r * 512;
  float4 a = *(const float4*)(row + lane * 4);
  float4 b = *(const float4*)(row + 256 + lane * 4);
  float m = fmaxf(fmaxf(fmaxf(a.x, a.y), fmaxf(a.z, a.w)),
                  fmaxf(fmaxf(b.x, b.y), fmaxf(b.z, b.w)));
#pragma unroll
  for (int off = 1; off < 64; off <<= 1) m = fmaxf(m, __shfl_xor(m, off));
  a.x = __expf(a.x - m); a.y = __expf(a.y - m);
  a.z = __expf(a.z - m); a.w = __expf(a.w - m);
  b.x = __expf(b.x - m); b.y = __expf(b.y - m);
  b.z = __expf(b.z - m); b.w = __expf(b.w - m);
  float s = a.x + a.y + a.z + a.w + b.x + b.y + b.z + b.w;
#pragma unroll
  for (int off = 1; off < 64; off <<= 1) s += __shfl_xor(s, off);
  float inv = 1.0f / s;
  a.x *= inv; a.y *= inv; a.z *= inv; a.w *= inv;
  b.x *= inv; b.y *= inv; b.z *= inv; b.w *= inv;
  *(float4*)(row + lane * 4) = a;
  *(float4*)(row + 256 + lane * 4) = b;
}

// ---------------- logits head: 16 tokens x 16 outputs per block ----------------
__global__ __launch_bounds__(256) void logits_kernel(
    const float* __restrict__ x, const float* __restrict__ Wa,
    const float* __restrict__ ba, float* __restrict__ out) {
  __shared__ float xs[16][260];
  __shared__ float was[4096];
  int tid = threadIdx.x;
  size_t t0 = (size_t)blockIdx.x * 16;
#pragma unroll
  for (int i = 0; i < 4; ++i) {
    int idx = tid + i * 256;  // float4 index over 1024
    int row = idx >> 6, c4 = (idx & 63) * 4;
    float4 v = *(const float4*)(x + (t0 + row) * 256 + c4);
    *(float4*)&xs[row][c4] = v;
    *(float4*)&was[idx * 4] = *(const float4*)(Wa + idx * 4);
  }
  __syncthreads();
  int o = tid & 15, tl = tid >> 4;
  float accv = ba[o];
#pragma unroll 8
  for (int k2 = 0; k2 < 256; ++k2)
    accv = fmaf(xs[tl][k2], was[k2 * 16 + o], accv);
  out[(t0 + tl) * 16 + o] = accv;
}

// ---------------- value head: wave per token ----------------
__global__ __launch_bounds__(256) void value_kernel(
    const float* __restrict__ x, const float* __restrict__ Wcr,
    const float* __restrict__ bcr, float* __restrict__ out) {
  int t = blockIdx.x * 4 + (threadIdx.x >> 6);
  int lane = threadIdx.x & 63;
  float4 xv = *(const float4*)(x + (size_t)t * 256 + lane * 4);
  float4 wv = *(const float4*)(Wcr + lane * 4);
  float s = xv.x * wv.x + xv.y * wv.y + xv.z * wv.z + xv.w * wv.w;
#pragma unroll
  for (int off = 1; off < 64; off <<= 1) s += __shfl_xor(s, off);
  if (lane == 0) out[t] = s + bcr[0];
}

// ---------------------------------------------------------------------------
extern "C" void kernel_launch(void* const* d_in, const int* in_sizes, int n_in,
                              void* d_out, int out_size, void* d_ws,
                              size_t ws_size, hipStream_t stream) {
  const float* obs = (const float*)d_in[0];
  // d_in[1] = dones_batch (unused by the reference)
  const float* We = (const float*)d_in[2];
  const float* be = (const float*)d_in[3];
  const float* Wc = (const float*)d_in[4];
  const float* bc = (const float*)d_in[5];
  const float* Wn = (const float*)d_in[6];
  const float* bn = (const float*)d_in[7];
  const float* Wb = (const float*)d_in[8];
  const float* bb = (const float*)d_in[9];
  const float* Wi = (const float*)d_in[10];
  const float* bi = (const float*)d_in[11];
  const float* Wq = (const float*)d_in[12];
  const float* bq = (const float*)d_in[13];
  const float* Wk = (const float*)d_in[14];
  const float* bk = (const float*)d_in[15];
  const float* Wv = (const float*)d_in[16];
  const float* bv = (const float*)d_in[17];
  const float* Wp = (const float*)d_in[18];
  const float* bp = (const float*)d_in[19];
  const float* Wa = (const float*)d_in[20];
  const float* ba = (const float*)d_in[21];
  const float* Wcr = (const float*)d_in[22];
  const float* bcr = (const float*)d_in[23];

  float* ws = (float*)d_ws;
  float* enc = ws;                       // 8388608
  float* msgagg = enc + 8388608;         // 4194304 (msg, then aggregated)
  float* qbuf = msgagg + 4194304;        // 4194304
  float* kbuf = qbuf + 4194304;          // 4194304
  float* vbuf = kbuf + 4194304;          // 4194304
  float* impb = vbuf + 4194304;          // 32768
  float* nrmb = impb + 32768;            // 32768
  float* wmb = nrmb + 32768;             // 32768
  float* bmb = wmb + 32768;              // 128
  float* sbuf = bmb + 128;               // chunk * 262144
  float* xbuf = qbuf;                    // alias over q+k (8388608 floats)

  build_wm<<<128, 256, 0, stream>>>(Wc, Wn, Wb, bc, bn, bb, wmb, bmb);

  // enc = relu(obs @ We + be)
  gemm_nn<1, 128, 128, 8, 8><<<dim3(2, 256, 1), 256, 0, stream>>>(
      obs, 128, 128, nullptr, 0, 128, We, 256, be, enc, 256, 0, 0, 0);
  // msg = enc @ Wm + bm
  gemm_nn<0, 128, 128, 8, 8><<<dim3(1, 256, 1), 256, 0, stream>>>(
      enc, 256, 256, nullptr, 0, 256, wmb, 128, bmb, msgagg, 128, 0, 0, 0);
  imp_nrm_kernel<<<8192, 256, 0, stream>>>(enc, obs, Wi, bi, impb, nrmb);
  // q = enc @ Wq + bq
  gemm_nn<0, 128, 128, 8, 8><<<dim3(1, 256, 1), 256, 0, stream>>>(
      enc, 256, 256, nullptr, 0, 256, Wq, 128, bq, qbuf, 128, 0, 0, 0);
  // k = msg @ Wk + bk
  gemm_nn<0, 128, 128, 8, 8><<<dim3(1, 256, 1), 256, 0, stream>>>(
      msgagg, 128, 128, nullptr, 0, 128, Wk, 128, bk, kbuf, 128, 0, 0, 0);
  // v = msg @ Wv + bv
  gemm_nn<0, 128, 128, 8, 8><<<dim3(1, 256, 1), 256, 0, stream>>>(
      msgagg, 128, 128, nullptr, 0, 128, Wv, 128, bv, vbuf, 128, 0, 0, 0);

  // attention, chunked over batches (scores buffer reused per chunk)
  long avail = (long)(ws_size / 4) - 25264256L;
  int chunk = (int)(avail / 262144L);
  if (chunk < 1) chunk = 1;
  if (chunk > 64) chunk = 64;
  for (int c0 = 0; c0 < 64; c0 += chunk) {
    int zb = (64 - c0 < chunk) ? (64 - c0) : chunk;
    scores_nt<<<dim3(4, 4, zb), 256, 0, stream>>>(qbuf, kbuf, obs, impb, nrmb,
                                                  sbuf, c0);
    softmax_rows<<<dim3(zb * 128), 256, 0, stream>>>(sbuf);
    // agg_b = P_b @ V_b
    gemm_nn<0, 64, 64, 4, 4><<<dim3(2, 8, zb), 256, 0, stream>>>(
        sbuf, 512, 512, nullptr, 0, 512, vbuf + (size_t)c0 * 65536, 128,
        nullptr, msgagg + (size_t)c0 * 65536, 128, 262144L, 65536L, 65536L);
  }

  // x = relu([enc | agg] @ Wp + bp)   (two-source K=384)
  gemm_nn<1, 128, 128, 8, 8><<<dim3(2, 256, 1), 256, 0, stream>>>(
      enc, 256, 256, msgagg, 128, 384, Wp, 256, bp, xbuf, 256, 0, 0, 0);

  logits_kernel<<<2048, 256, 0, stream>>>(xbuf, Wa, ba, (float*)d_out);
  value_kernel<<<8192, 256, 0, stream>>>(xbuf, Wcr, bcr,
                                         (float*)d_out + 524288);
}

// Round 2
// 301.770 us; speedup vs baseline: 1.9429x; 1.9429x over previous
//
#include <hip/hip_runtime.h>
#include <math.h>

// ---------------------------------------------------------------------------
// HADCommNetwork forward, bf16-MFMA version.
// B=64, N=512, OBS=128, H=256, M=128, ACT=16, T=32768.
// All GEMMs: NT form C[m][n] = sum_k A[m][k]*Bt[n][k] via mfma_f32_16x16x32_bf16.
// Tile 64x128, BK=64, 256 thr = 4 waves of 32x64 (2x4 MFMA accs).
// Scores fold imp/rsqrtD/cosine scaling into As/Bs operand buffers (K=256).
// Softmax writes P bf16 in place over the fp32 score rows (first half bytes).
// ---------------------------------------------------------------------------

typedef __attribute__((ext_vector_type(8))) short short8;
typedef __attribute__((ext_vector_type(4))) float f32x4;

#define RSQRT_D 0.08838834764831843f  // 1/sqrt(128)

__device__ __forceinline__ unsigned short f2bf(float f) {
  union { float f; unsigned u; } v; v.f = f;
  return (unsigned short)((v.u + 0x7FFFu + ((v.u >> 16) & 1u)) >> 16);
}
__device__ __forceinline__ float bf2f(unsigned short h) {
  union { unsigned u; float f; } v; v.u = ((unsigned)h) << 16;
  return v.f;
}
__device__ __forceinline__ unsigned pack2(float a, float b) {
  return (unsigned)f2bf(a) | ((unsigned)f2bf(b) << 16);
}

// ---------------- weight prep ----------------
// Wt[n][k] = bf16(W[k][n]); grid covers N*K elements.
__global__ __launch_bounds__(256) void wt_cast(const float* __restrict__ W,
                                               unsigned short* __restrict__ Wt,
                                               int K, int N) {
  int idx = blockIdx.x * 256 + threadIdx.x;
  int n = idx / K, k = idx - n * K;
  Wt[idx] = f2bf(W[(size_t)k * N + n]);
}

// WmT[d][h] packed from Wc|Wn|Wb (transposed), bm packed from bc|bn|bb.
__global__ __launch_bounds__(256) void pack_wm(
    const float* __restrict__ Wc, const float* __restrict__ Wn,
    const float* __restrict__ Wb, const float* __restrict__ bc,
    const float* __restrict__ bn, const float* __restrict__ bb,
    unsigned short* __restrict__ WmT, float* __restrict__ bm) {
  int idx = blockIdx.x * 256 + threadIdx.x;  // 128*256
  int d = idx >> 8, h = idx & 255;
  float v = (d < 32) ? Wc[h * 32 + d]
          : (d < 96) ? Wn[h * 64 + (d - 32)]
                     : Wb[h * 32 + (d - 96)];
  WmT[idx] = f2bf(v);
  if (blockIdx.x == 0 && idx < 128)
    bm[idx] = (idx < 32) ? bc[idx] : (idx < 96) ? bn[idx - 32] : bb[idx - 96];
}

// ---------------- obs prep: norms + bf16 conversions ----------------
// obs_bf = bf16(obs); As[:,128:256] = bf16(0.5*obs/(n+e)); Bs[:,128:256] = bf16(obs/(n+e))
__global__ __launch_bounds__(256) void prep_obs(
    const float* __restrict__ obs, unsigned short* __restrict__ obs_bf,
    unsigned short* __restrict__ As, unsigned short* __restrict__ Bs) {
  int t = blockIdx.x * 4 + (threadIdx.x >> 6);
  int lane = threadIdx.x & 63;
  const float* row = obs + (size_t)t * 128;
  float2 o = *(const float2*)(row + lane * 2);
  float s2 = o.x * o.x + o.y * o.y;
#pragma unroll
  for (int off = 1; off < 64; off <<= 1) s2 += __shfl_xor(s2, off);
  float inv = 1.f / (sqrtf(s2) + 1e-8f);
  ((unsigned*)obs_bf)[(size_t)t * 64 + lane] = pack2(o.x, o.y);
  ((unsigned*)As)[(size_t)t * 128 + 64 + lane] =
      pack2(o.x * 0.5f * inv, o.y * 0.5f * inv);
  ((unsigned*)Bs)[(size_t)t * 128 + 64 + lane] = pack2(o.x * inv, o.y * inv);
}

// ---------------- importance ----------------
__global__ __launch_bounds__(256) void imp_kernel(
    const unsigned short* __restrict__ enc, const float* __restrict__ Wi,
    const float* __restrict__ bi, float* __restrict__ impA,
    float* __restrict__ impB) {
  int t = blockIdx.x * 4 + (threadIdx.x >> 6);
  int lane = threadIdx.x & 63;
  const unsigned* eu = (const unsigned*)(enc + (size_t)t * 256);
  unsigned u0 = eu[lane * 2], u1 = eu[lane * 2 + 1];
  float4 w = *(const float4*)(Wi + lane * 4);
  float s = bf2f((unsigned short)(u0 & 0xFFFF)) * w.x +
            bf2f((unsigned short)(u0 >> 16)) * w.y +
            bf2f((unsigned short)(u1 & 0xFFFF)) * w.z +
            bf2f((unsigned short)(u1 >> 16)) * w.w;
#pragma unroll
  for (int off = 1; off < 64; off <<= 1) s += __shfl_xor(s, off);
  if (lane == 0) {
    float sg = 1.0f / (1.0f + __expf(-(s + bi[0])));
    impA[t] = sg * RSQRT_D;
    impB[t] = sg;
  }
}

// ---------------- generic NT MFMA GEMM ----------------
// C = ACT([A1|A2] @ Bt^T + bias) [* scale(row)], OUTF32 selects f32 vs bf16 out.
template <int ACT, int OUTF32, int SCALE>
__global__ __launch_bounds__(256, 2) void gemm_nt(
    const unsigned short* __restrict__ A1, int lda1, int K1,
    const unsigned short* __restrict__ A2, int lda2, int Ktot,
    const unsigned short* __restrict__ Bt, int ldb,
    const float* __restrict__ bias, const float* __restrict__ scale,
    void* __restrict__ Cout, int ldc, long sA, long sB, long sC) {
  __shared__ unsigned short Asr[64][72];   // pad to 72 shorts: balanced banks
  __shared__ unsigned short Bsr[128][72];
  const int tid = threadIdx.x;
  const int lane = tid & 63, wave = tid >> 6;
  const int quad = lane >> 4, l16 = lane & 15;
  const int wm = wave & 1, wn = wave >> 1;
  const int bm = blockIdx.y * 64, bn = blockIdx.x * 128;
  const int z = blockIdx.z;
  const unsigned short* Az = A1 + (size_t)z * sA;
  const unsigned short* Bz = Bt + (size_t)z * sB;

  f32x4 acc[2][4];
#pragma unroll
  for (int i = 0; i < 2; ++i)
#pragma unroll
    for (int j = 0; j < 4; ++j) acc[i][j] = (f32x4){0.f, 0.f, 0.f, 0.f};

  const int ar = tid >> 3, ac = tid & 7;
  for (int kt = 0; kt < Ktot; kt += 64) {
    const unsigned short* Asrc;
    int lda, kloc;
    if (kt < K1) { Asrc = Az; lda = lda1; kloc = kt; }
    else         { Asrc = A2; lda = lda2; kloc = kt - K1; }
#pragma unroll
    for (int it = 0; it < 2; ++it) {
      int r = ar + it * 32;
      uint4 v = *(const uint4*)(Asrc + (size_t)(bm + r) * lda + kloc + ac * 8);
      *(uint4*)&Asr[r][ac * 8] = v;
    }
#pragma unroll
    for (int it = 0; it < 4; ++it) {
      int r = ar + it * 32;
      uint4 v = *(const uint4*)(Bz + (size_t)(bn + r) * ldb + kt + ac * 8);
      *(uint4*)&Bsr[r][ac * 8] = v;
    }
    __syncthreads();
#pragma unroll
    for (int ks = 0; ks < 64; ks += 32) {
      short8 af[2], bfr[4];
#pragma unroll
      for (int i = 0; i < 2; ++i)
        af[i] = *(const short8*)&Asr[wm * 32 + i * 16 + l16][ks + quad * 8];
#pragma unroll
      for (int j = 0; j < 4; ++j)
        bfr[j] = *(const short8*)&Bsr[wn * 64 + j * 16 + l16][ks + quad * 8];
#pragma unroll
      for (int i = 0; i < 2; ++i)
#pragma unroll
        for (int j = 0; j < 4; ++j)
          acc[i][j] = __builtin_amdgcn_mfma_f32_16x16x32_bf16(af[i], bfr[j],
                                                              acc[i][j], 0, 0, 0);
    }
    __syncthreads();
  }
  const int colb = bn + wn * 64 + l16;
#pragma unroll
  for (int i = 0; i < 2; ++i) {
    const int rowb = bm + wm * 32 + i * 16 + quad * 4;
    float sc[4];
    if (SCALE) {
#pragma unroll
      for (int r = 0; r < 4; ++r) sc[r] = scale[rowb + r];
    }
#pragma unroll
    for (int j = 0; j < 4; ++j) {
      const int col = colb + j * 16;
      const float bv = bias ? bias[col] : 0.f;
#pragma unroll
      for (int r = 0; r < 4; ++r) {
        float v = acc[i][j][r] + bv;
        if (ACT) v = fmaxf(v, 0.f);
        if (SCALE) v *= sc[r];
        if (OUTF32)
          ((float*)Cout)[(size_t)z * sC + (size_t)(rowb + r) * ldc + col] = v;
        else
          ((unsigned short*)Cout)[(size_t)z * sC + (size_t)(rowb + r) * ldc + col] =
              f2bf(v);
      }
    }
  }
}

// ---------------- V transpose: v[T x 128] -> vT[64][128][512] ----------------
__global__ __launch_bounds__(256) void vt_trans(const unsigned short* __restrict__ v,
                                                unsigned short* __restrict__ vT) {
  __shared__ unsigned short t[64][72];
  int b = blockIdx.z, n0 = blockIdx.x * 64, d0 = blockIdx.y * 64;
  int tid = threadIdx.x;
#pragma unroll
  for (int it = 0; it < 2; ++it) {
    int idx = tid + it * 256;
    int r = idx >> 3, c = idx & 7;
    uint4 vv = *(const uint4*)(v + ((size_t)b * 512 + n0 + r) * 128 + d0 + c * 8);
    *(uint4*)&t[r][c * 8] = vv;
  }
  __syncthreads();
#pragma unroll
  for (int it = 0; it < 2; ++it) {
    int idx = tid + it * 256;
    int d = idx >> 3, c = idx & 7;
    uint4 o;
    o.x = (unsigned)t[c * 8 + 0][d] | ((unsigned)t[c * 8 + 1][d] << 16);
    o.y = (unsigned)t[c * 8 + 2][d] | ((unsigned)t[c * 8 + 3][d] << 16);
    o.z = (unsigned)t[c * 8 + 4][d] | ((unsigned)t[c * 8 + 5][d] << 16);
    o.w = (unsigned)t[c * 8 + 6][d] | ((unsigned)t[c * 8 + 7][d] << 16);
    *(uint4*)(vT + ((size_t)b * 128 + d0 + d) * 512 + n0 + c * 8) = o;
  }
}

// ---------------- softmax: fp32 row -> bf16 P in place (first half bytes) ----
__global__ __launch_bounds__(256) void softmax_p(float* __restrict__ S) {
  int r = blockIdx.x * 4 + (threadIdx.x >> 6);
  int lane = threadIdx.x & 63;
  float* row = S + (size_t)r * 512;
  float4 a = *(const float4*)(row + lane * 4);
  float4 b = *(const float4*)(row + 256 + lane * 4);
  float m = fmaxf(fmaxf(fmaxf(a.x, a.y), fmaxf(a.z, a.w)),
                  fmaxf(fmaxf(b.x, b.y), fmaxf(b.z, b.w)));
#pragma unroll
  for (int off = 1; off < 64; off <<= 1) m = fmaxf(m, __shfl_xor(m, off));
  a.x = __expf(a.x - m); a.y = __expf(a.y - m);
  a.z = __expf(a.z - m); a.w = __expf(a.w - m);
  b.x = __expf(b.x - m); b.y = __expf(b.y - m);
  b.z = __expf(b.z - m); b.w = __expf(b.w - m);
  float s = a.x + a.y + a.z + a.w + b.x + b.y + b.z + b.w;
#pragma unroll
  for (int off = 1; off < 64; off <<= 1) s += __shfl_xor(s, off);
  float inv = 1.0f / s;
  unsigned short* prow = (unsigned short*)row;
  uint2 pa, pb;
  pa.x = pack2(a.x * inv, a.y * inv); pa.y = pack2(a.z * inv, a.w * inv);
  pb.x = pack2(b.x * inv, b.y * inv); pb.y = pack2(b.z * inv, b.w * inv);
  *(uint2*)(prow + lane * 4) = pa;
  *(uint2*)(prow + 256 + lane * 4) = pb;
}

// ---------------- heads ----------------
__global__ __launch_bounds__(256) void logits_head(
    const unsigned short* __restrict__ x, const float* __restrict__ Wa,
    const float* __restrict__ ba, float* __restrict__ out) {
  __shared__ float xs[16][264];
  __shared__ float was[4096];
  int tid = threadIdx.x;
  size_t t0 = (size_t)blockIdx.x * 16;
#pragma unroll
  for (int i = 0; i < 4; ++i) {
    int idx = tid + i * 256;  // 0..1023
    int row = idx >> 6, c4 = (idx & 63) * 4;
    uint2 u = *(const uint2*)(x + (t0 + row) * 256 + c4);
    xs[row][c4 + 0] = bf2f((unsigned short)(u.x & 0xFFFF));
    xs[row][c4 + 1] = bf2f((unsigned short)(u.x >> 16));
    xs[row][c4 + 2] = bf2f((unsigned short)(u.y & 0xFFFF));
    xs[row][c4 + 3] = bf2f((unsigned short)(u.y >> 16));
    *(float4*)&was[idx * 4] = *(const float4*)(Wa + idx * 4);
  }
  __syncthreads();
  int o = tid & 15, tl = tid >> 4;
  float accv = ba[o];
#pragma unroll 8
  for (int k2 = 0; k2 < 256; ++k2)
    accv = fmaf(xs[tl][k2], was[k2 * 16 + o], accv);
  out[(t0 + tl) * 16 + o] = accv;
}

__global__ __launch_bounds__(256) void value_head(
    const unsigned short* __restrict__ x, const float* __restrict__ Wcr,
    const float* __restrict__ bcr, float* __restrict__ out) {
  int t = blockIdx.x * 4 + (threadIdx.x >> 6);
  int lane = threadIdx.x & 63;
  const unsigned* xu = (const unsigned*)(x + (size_t)t * 256);
  unsigned u0 = xu[lane * 2], u1 = xu[lane * 2 + 1];
  float4 w = *(const float4*)(Wcr + lane * 4);
  float s = bf2f((unsigned short)(u0 & 0xFFFF)) * w.x +
            bf2f((unsigned short)(u0 >> 16)) * w.y +
            bf2f((unsigned short)(u1 & 0xFFFF)) * w.z +
            bf2f((unsigned short)(u1 >> 16)) * w.w;
#pragma unroll
  for (int off = 1; off < 64; off <<= 1) s += __shfl_xor(s, off);
  if (lane == 0) out[t] = s + bcr[0];
}

// ---------------------------------------------------------------------------
extern "C" void kernel_launch(void* const* d_in, const int* in_sizes, int n_in,
                              void* d_out, int out_size, void* d_ws,
                              size_t ws_size, hipStream_t stream) {
  const float* obs = (const float*)d_in[0];
  const float* We = (const float*)d_in[2];
  const float* be = (const float*)d_in[3];
  const float* Wc = (const float*)d_in[4];
  const float* bc = (const float*)d_in[5];
  const float* Wn = (const float*)d_in[6];
  const float* bn = (const float*)d_in[7];
  const float* Wb = (const float*)d_in[8];
  const float* bb = (const float*)d_in[9];
  const float* Wi = (const float*)d_in[10];
  const float* bi = (const float*)d_in[11];
  const float* Wq = (const float*)d_in[12];
  const float* bq = (const float*)d_in[13];
  const float* Wk = (const float*)d_in[14];
  const float* bk = (const float*)d_in[15];
  const float* Wv = (const float*)d_in[16];
  const float* bv = (const float*)d_in[17];
  const float* Wp = (const float*)d_in[18];
  const float* bp = (const float*)d_in[19];
  const float* Wa = (const float*)d_in[20];
  const float* ba = (const float*)d_in[21];
  const float* Wcr = (const float*)d_in[22];
  const float* bcr = (const float*)d_in[23];

  char* base = (char*)d_ws;
  unsigned short* enc_bf = (unsigned short*)(base);                  // 16.78 MB
  unsigned short* As     = (unsigned short*)(base + 16777216);       // 16.78 MB
  unsigned short* Bs     = (unsigned short*)(base + 33554432);       // 16.78 MB
  unsigned short* obsagg = (unsigned short*)(base + 50331648);       // 8.39 MB (obs_bf, then agg)
  unsigned short* msgv   = (unsigned short*)(base + 58720256);       // 16.78 MB (msg|v, then x)
  unsigned short* msg_bf = msgv;
  unsigned short* v_bf   = msgv + 4194304;
  unsigned short* x_bf   = msgv;
  unsigned short* vT     = (unsigned short*)(base + 75497472);       // 8.39 MB
  float* impA            = (float*)(base + 83886080);                // 128 KB
  float* impB            = (float*)(base + 84017152);                // 128 KB
  unsigned short* WeT    = (unsigned short*)(base + 84148224);       // 64 KB
  unsigned short* WmT    = (unsigned short*)(base + 84213760);
  unsigned short* WqT    = (unsigned short*)(base + 84279296);
  unsigned short* WkT    = (unsigned short*)(base + 84344832);
  unsigned short* WvT    = (unsigned short*)(base + 84377600);
  unsigned short* WpT    = (unsigned short*)(base + 84410368);       // 192 KB
  float* bmb             = (float*)(base + 84606976);                // 512 B
  float* sbuf            = (float*)(base + 84607488);                // 67.1 MB

  // weight prep
  wt_cast<<<128, 256, 0, stream>>>(We, WeT, 128, 256);   // WeT[256][128]
  wt_cast<<<128, 256, 0, stream>>>(Wq, WqT, 256, 128);   // WqT[128][256]
  wt_cast<<<64, 256, 0, stream>>>(Wk, WkT, 128, 128);
  wt_cast<<<64, 256, 0, stream>>>(Wv, WvT, 128, 128);
  wt_cast<<<384, 256, 0, stream>>>(Wp, WpT, 384, 256);   // WpT[256][384]
  pack_wm<<<128, 256, 0, stream>>>(Wc, Wn, Wb, bc, bn, bb, WmT, bmb);
  prep_obs<<<8192, 256, 0, stream>>>(obs, obsagg, As, Bs);

  // enc = relu(obs @ We + be)  [T x 256]
  gemm_nt<1, 0, 0><<<dim3(2, 512, 1), 256, 0, stream>>>(
      obsagg, 128, 128, nullptr, 0, 128, WeT, 128, be, nullptr, enc_bf, 256,
      0L, 0L, 0L);
  imp_kernel<<<8192, 256, 0, stream>>>(enc_bf, Wi, bi, impA, impB);
  // msg = enc @ Wm + bm
  gemm_nt<0, 0, 0><<<dim3(1, 512, 1), 256, 0, stream>>>(
      enc_bf, 256, 256, nullptr, 0, 256, WmT, 256, bmb, nullptr, msg_bf, 128,
      0L, 0L, 0L);
  // As[:,0:128] = (enc @ Wq + bq) * imp * rsqrtD
  gemm_nt<0, 0, 1><<<dim3(1, 512, 1), 256, 0, stream>>>(
      enc_bf, 256, 256, nullptr, 0, 256, WqT, 256, bq, impA, As, 256,
      0L, 0L, 0L);
  // Bs[:,0:128] = (msg @ Wk + bk) * imp
  gemm_nt<0, 0, 1><<<dim3(1, 512, 1), 256, 0, stream>>>(
      msg_bf, 128, 128, nullptr, 0, 128, WkT, 128, bk, impB, Bs, 256,
      0L, 0L, 0L);
  // v = msg @ Wv + bv
  gemm_nt<0, 0, 0><<<dim3(1, 512, 1), 256, 0, stream>>>(
      msg_bf, 128, 128, nullptr, 0, 128, WvT, 128, bv, nullptr, v_bf, 128,
      0L, 0L, 0L);
  vt_trans<<<dim3(8, 2, 64), 256, 0, stream>>>(v_bf, vT);

  // scores: batched NT GEMM, K=256, fp32 out
  gemm_nt<0, 1, 0><<<dim3(4, 8, 64), 256, 0, stream>>>(
      As, 256, 256, nullptr, 0, 256, Bs, 256, nullptr, nullptr, sbuf, 512,
      131072L, 131072L, 262144L);
  softmax_p<<<8192, 256, 0, stream>>>(sbuf);
  // agg = P @ V  (P bf16 rows at stride 1024 over sbuf bytes)
  gemm_nt<0, 0, 0><<<dim3(1, 8, 64), 256, 0, stream>>>(
      (const unsigned short*)sbuf, 1024, 512, nullptr, 0, 512, vT, 512,
      nullptr, nullptr, obsagg, 128, 524288L, 65536L, 65536L);

  // x = relu([enc | agg] @ Wp + bp)
  gemm_nt<1, 0, 0><<<dim3(2, 512, 1), 256, 0, stream>>>(
      enc_bf, 256, 256, obsagg, 128, 384, WpT, 384, bp, nullptr, x_bf, 256,
      0L, 0L, 0L);

  logits_head<<<2048, 256, 0, stream>>>(x_bf, Wa, ba, (float*)d_out);
  value_head<<<8192, 256, 0, stream>>>(x_bf, Wcr, bcr, (float*)d_out + 524288);
}

// Round 3
// 249.091 us; speedup vs baseline: 2.3538x; 1.2115x over previous
//
#include <hip/hip_runtime.h>
#include <math.h>

// ---------------------------------------------------------------------------
// HADCommNetwork forward, bf16-MFMA + flash-fused attention.
// B=64, N=512, OBS=128, H=256, M=128, ACT=16, T=32768.
// Pipeline (9 launches):
//   prep_w | prep_obs | enc GEMM | imp | (msg|q) GEMM | (k|v) GEMM |
//   flash attention | x GEMM | heads
// All GEMMs NT via mfma_f32_16x16x32_bf16, tile 64x128, BK=64, 4 waves.
// Scores = plain NT GEMM over virtual K=256 (q*imp*rsqrtD | 0.5*obs/nrm) x
// (k*imp | obs/nrm), computed inside flash with online softmax (S fp32 regs).
// ---------------------------------------------------------------------------

typedef __attribute__((ext_vector_type(8))) short short8;
typedef __attribute__((ext_vector_type(4))) float f32x4;

#define RSQRT_D 0.08838834764831843f  // 1/sqrt(128)

__device__ __forceinline__ unsigned short f2bf(float f) {
  union { float f; unsigned u; } v; v.f = f;
  return (unsigned short)((v.u + 0x7FFFu + ((v.u >> 16) & 1u)) >> 16);
}
__device__ __forceinline__ float bf2f(unsigned short h) {
  union { unsigned u; float f; } v; v.u = ((unsigned)h) << 16;
  return v.f;
}
__device__ __forceinline__ unsigned pack2(float a, float b) {
  return (unsigned)f2bf(a) | ((unsigned)f2bf(b) << 16);
}

// ---------------- consolidated weight prep ----------------
// WeT[256][128], Wmq[256][256] (rows 0:128 = packed Wm^T, 128:256 = Wq^T),
// Wkv[256][128] (rows 0:128 = Wk^T, 128:256 = Wv^T), WpT[256][384], bm[128].
__global__ __launch_bounds__(256) void prep_w(
    const float* __restrict__ We, const float* __restrict__ Wq,
    const float* __restrict__ Wk, const float* __restrict__ Wv,
    const float* __restrict__ Wp, const float* __restrict__ Wc,
    const float* __restrict__ Wn, const float* __restrict__ Wb,
    const float* __restrict__ bc, const float* __restrict__ bn,
    const float* __restrict__ bb, unsigned short* __restrict__ WeT,
    unsigned short* __restrict__ Wmq, unsigned short* __restrict__ Wkv,
    unsigned short* __restrict__ WpT, float* __restrict__ bm) {
  int idx = blockIdx.x * 256 + threadIdx.x;
  if (idx < 32768) {                 // WeT[n 256][k 128]
    int n = idx >> 7, k = idx & 127;
    WeT[idx] = f2bf(We[k * 256 + n]);
  } else if (idx < 65536) {          // Wmq rows 0..127: WmT[d 128][h 256]
    int i = idx - 32768;
    int d = i >> 8, h = i & 255;
    float v = (d < 32)   ? Wc[h * 32 + d]
            : (d < 96)   ? Wn[h * 64 + (d - 32)]
                         : Wb[h * 32 + (d - 96)];
    Wmq[i] = f2bf(v);
  } else if (idx < 98304) {          // Wmq rows 128..255: WqT[n 128][k 256]
    int i = idx - 65536;
    int n = i >> 8, k = i & 255;
    Wmq[32768 + i] = f2bf(Wq[k * 128 + n]);
  } else if (idx < 114688) {         // Wkv rows 0..127: WkT[128][128]
    int i = idx - 98304;
    int n = i >> 7, k = i & 127;
    Wkv[i] = f2bf(Wk[k * 128 + n]);
  } else if (idx < 131072) {         // Wkv rows 128..255: WvT[128][128]
    int i = idx - 114688;
    int n = i >> 7, k = i & 127;
    Wkv[16384 + i] = f2bf(Wv[k * 128 + n]);
  } else if (idx < 229376) {         // WpT[n 256][k 384]
    int i = idx - 131072;
    int n = i / 384, k = i - n * 384;
    WpT[i] = f2bf(Wp[k * 256 + n]);
  } else if (idx < 229504) {         // bm
    int i = idx - 229376;
    bm[i] = (i < 32) ? bc[i] : (i < 96) ? bn[i - 32] : bb[i - 96];
  }
}

// ---------------- obs prep: norms + bf16 conversions ----------------
__global__ __launch_bounds__(256) void prep_obs(
    const float* __restrict__ obs, unsigned short* __restrict__ obs_bf,
    unsigned short* __restrict__ As, unsigned short* __restrict__ Bs) {
  int t = blockIdx.x * 4 + (threadIdx.x >> 6);
  int lane = threadIdx.x & 63;
  const float* row = obs + (size_t)t * 128;
  float2 o = *(const float2*)(row + lane * 2);
  float s2 = o.x * o.x + o.y * o.y;
#pragma unroll
  for (int off = 1; off < 64; off <<= 1) s2 += __shfl_xor(s2, off);
  float inv = 1.f / (sqrtf(s2) + 1e-8f);
  ((unsigned*)obs_bf)[(size_t)t * 64 + lane] = pack2(o.x, o.y);
  ((unsigned*)As)[(size_t)t * 128 + 64 + lane] =
      pack2(o.x * 0.5f * inv, o.y * 0.5f * inv);
  ((unsigned*)Bs)[(size_t)t * 128 + 64 + lane] = pack2(o.x * inv, o.y * inv);
}

// ---------------- importance ----------------
__global__ __launch_bounds__(256) void imp_kernel(
    const unsigned short* __restrict__ enc, const float* __restrict__ Wi,
    const float* __restrict__ bi, float* __restrict__ impA,
    float* __restrict__ impB) {
  int t = blockIdx.x * 4 + (threadIdx.x >> 6);
  int lane = threadIdx.x & 63;
  const unsigned* eu = (const unsigned*)(enc + (size_t)t * 256);
  unsigned u0 = eu[lane * 2], u1 = eu[lane * 2 + 1];
  float4 w = *(const float4*)(Wi + lane * 4);
  float s = bf2f((unsigned short)(u0 & 0xFFFF)) * w.x +
            bf2f((unsigned short)(u0 >> 16)) * w.y +
            bf2f((unsigned short)(u1 & 0xFFFF)) * w.z +
            bf2f((unsigned short)(u1 >> 16)) * w.w;
#pragma unroll
  for (int off = 1; off < 64; off <<= 1) s += __shfl_xor(s, off);
  if (lane == 0) {
    float sg = 1.0f / (1.0f + __expf(-(s + bi[0])));
    impA[t] = sg * RSQRT_D;
    impB[t] = sg;
  }
}

// ---------------- dual-epilogue NT MFMA GEMM ----------------
// Modes: 0 = bf16(+bias), 1 = relu bf16, 2 = bf16*scale[row] (+bias),
//        3 = transposed write into vT[b][d][tok] (+bias).
template <int MODE>
__device__ __forceinline__ void epi_store(unsigned short* out, int ldc,
                                          const float* bias,
                                          const float* scale, int rowb,
                                          int col, const f32x4& a) {
  const float bv = bias ? bias[col] : 0.f;
  if constexpr (MODE == 3) {
    unsigned short t0 = f2bf(a[0] + bv), t1 = f2bf(a[1] + bv);
    unsigned short t2 = f2bf(a[2] + bv), t3 = f2bf(a[3] + bv);
    uint2 o;
    o.x = (unsigned)t0 | ((unsigned)t1 << 16);
    o.y = (unsigned)t2 | ((unsigned)t3 << 16);
    *(uint2*)(out + ((size_t)(rowb >> 9) * 128 + col) * 512 + (rowb & 511)) = o;
  } else {
#pragma unroll
    for (int r = 0; r < 4; ++r) {
      float v = a[r] + bv;
      if constexpr (MODE == 1) v = fmaxf(v, 0.f);
      if constexpr (MODE == 2) v *= scale[rowb + r];
      out[(size_t)(rowb + r) * ldc + col] = f2bf(v);
    }
  }
}

template <int M0, int M1>
__global__ __launch_bounds__(256, 2) void gemm_dual(
    const unsigned short* __restrict__ A1, int lda1, int K1,
    const unsigned short* __restrict__ A2, int lda2, int Ktot,
    const unsigned short* __restrict__ Bt, int ldb,
    const float* __restrict__ bias0, const float* __restrict__ bias1,
    const float* __restrict__ scale, unsigned short* __restrict__ out0,
    int ldc0, unsigned short* __restrict__ out1, int ldc1, int xsplit) {
  __shared__ unsigned short Asr[64][72];
  __shared__ unsigned short Bsr[128][72];
  const int tid = threadIdx.x;
  const int lane = tid & 63, wave = tid >> 6;
  const int quad = lane >> 4, l16 = lane & 15;
  const int wm = wave & 1, wn = wave >> 1;
  const int bm = blockIdx.y * 64, bn = blockIdx.x * 128;

  f32x4 acc[2][4];
#pragma unroll
  for (int i = 0; i < 2; ++i)
#pragma unroll
    for (int j = 0; j < 4; ++j) acc[i][j] = (f32x4){0.f, 0.f, 0.f, 0.f};

  const int ar = tid >> 3, ac = tid & 7;
  for (int kt = 0; kt < Ktot; kt += 64) {
    const unsigned short* Asrc;
    int lda, kloc;
    if (kt < K1) { Asrc = A1; lda = lda1; kloc = kt; }
    else         { Asrc = A2; lda = lda2; kloc = kt - K1; }
#pragma unroll
    for (int it = 0; it < 2; ++it) {
      int r = ar + it * 32;
      uint4 v = *(const uint4*)(Asrc + (size_t)(bm + r) * lda + kloc + ac * 8);
      *(uint4*)&Asr[r][ac * 8] = v;
    }
#pragma unroll
    for (int it = 0; it < 4; ++it) {
      int r = ar + it * 32;
      uint4 v = *(const uint4*)(Bt + (size_t)(bn + r) * ldb + kt + ac * 8);
      *(uint4*)&Bsr[r][ac * 8] = v;
    }
    __syncthreads();
#pragma unroll
    for (int ks = 0; ks < 64; ks += 32) {
      short8 af[2], bfr[4];
#pragma unroll
      for (int i = 0; i < 2; ++i)
        af[i] = *(const short8*)&Asr[wm * 32 + i * 16 + l16][ks + quad * 8];
#pragma unroll
      for (int j = 0; j < 4; ++j)
        bfr[j] = *(const short8*)&Bsr[wn * 64 + j * 16 + l16][ks + quad * 8];
#pragma unroll
      for (int i = 0; i < 2; ++i)
#pragma unroll
        for (int j = 0; j < 4; ++j)
          acc[i][j] = __builtin_amdgcn_mfma_f32_16x16x32_bf16(af[i], bfr[j],
                                                              acc[i][j], 0, 0, 0);
    }
    __syncthreads();
  }
  const int colb = bn + wn * 64 + l16;
#pragma unroll
  for (int i = 0; i < 2; ++i) {
    const int rowb = bm + wm * 32 + i * 16 + quad * 4;
#pragma unroll
    for (int j = 0; j < 4; ++j) {
      const int col = colb + j * 16;
      if (col < xsplit)
        epi_store<M0>(out0, ldc0, bias0, scale, rowb, col, acc[i][j]);
      else
        epi_store<M1>(out1, ldc1, bias1, scale, rowb, col - xsplit, acc[i][j]);
    }
  }
}

// ---------------- flash attention ----------------
// Per block: one batch b, one 64-row Q tile. Online softmax over 4 key-tiles
// of 128. A-operand (As rows) held in registers; S fp32 in regs; P -> LDS
// bf16 (A-layout) -> PV MFMA with vT as B-operand.
__global__ __launch_bounds__(256, 2) void flash_attn(
    const unsigned short* __restrict__ As, const unsigned short* __restrict__ Bs,
    const unsigned short* __restrict__ vT, unsigned short* __restrict__ agg) {
  __shared__ unsigned short Ub[128][130];  // B-tile half-K / V-tile
  __shared__ unsigned short Up[64][130];   // P tile (A-operand layout)
  __shared__ float redm[2][64];
  __shared__ float reds[2][64];
  const int tid = threadIdx.x;
  const int lane = tid & 63, wave = tid >> 6;
  const int quad = lane >> 4, l16 = lane & 15;
  const int wm = wave & 1, wn = wave >> 1;
  const int b = blockIdx.y;
  const int q0 = blockIdx.x * 64;
  const size_t tokA = (size_t)b * 512 + q0;

  // A fragments: rows wm*32 + i*16 + l16, k = kc*32 + quad*8 (K=256)
  short8 af[2][8];
#pragma unroll
  for (int i = 0; i < 2; ++i)
#pragma unroll
    for (int kc = 0; kc < 8; ++kc)
      af[i][kc] = *(const short8*)(As + (tokA + wm * 32 + i * 16 + l16) * 256 +
                                   kc * 32 + quad * 8);

  f32x4 oacc[2][4];
  float m_run[2][4], l_run[2][4];
#pragma unroll
  for (int i = 0; i < 2; ++i)
#pragma unroll
    for (int r = 0; r < 4; ++r) { m_run[i][r] = -1e30f; l_run[i][r] = 0.f; }
#pragma unroll
  for (int i = 0; i < 2; ++i)
#pragma unroll
    for (int j = 0; j < 4; ++j) oacc[i][j] = (f32x4){0.f, 0.f, 0.f, 0.f};

  for (int kt = 0; kt < 4; ++kt) {
    const int k0 = kt * 128;
    f32x4 s[2][4];
#pragma unroll
    for (int i = 0; i < 2; ++i)
#pragma unroll
      for (int j = 0; j < 4; ++j) s[i][j] = (f32x4){0.f, 0.f, 0.f, 0.f};

    // ---- QK^T over K=256 in two 128-halves ----
#pragma unroll
    for (int kh = 0; kh < 2; ++kh) {
      __syncthreads();  // protect Ub from previous readers
#pragma unroll
      for (int it = 0; it < 8; ++it) {
        int idx = tid + it * 256;
        int r = idx >> 4, c = idx & 15;
        *(uint4*)&Ub[r][c * 8] =
            *(const uint4*)(Bs + ((size_t)b * 512 + k0 + r) * 256 + kh * 128 +
                            c * 8);
      }
      __syncthreads();
#pragma unroll
      for (int kk = 0; kk < 4; ++kk) {
        short8 bfr[4];
#pragma unroll
        for (int j = 0; j < 4; ++j)
          bfr[j] = *(const short8*)&Ub[wn * 64 + j * 16 + l16][kk * 32 + quad * 8];
#pragma unroll
        for (int i = 0; i < 2; ++i)
#pragma unroll
          for (int j = 0; j < 4; ++j)
            s[i][j] = __builtin_amdgcn_mfma_f32_16x16x32_bf16(
                af[i][kh * 4 + kk], bfr[j], s[i][j], 0, 0, 0);
      }
    }

    // ---- online softmax update ----
    float mt[2][4];
#pragma unroll
    for (int i = 0; i < 2; ++i)
#pragma unroll
      for (int r = 0; r < 4; ++r) {
        float mv = fmaxf(fmaxf(s[i][0][r], s[i][1][r]),
                         fmaxf(s[i][2][r], s[i][3][r]));
#pragma unroll
        for (int off = 1; off < 16; off <<= 1)
          mv = fmaxf(mv, __shfl_xor(mv, off));
        mt[i][r] = mv;
      }
    if (l16 == 0) {
#pragma unroll
      for (int i = 0; i < 2; ++i)
#pragma unroll
        for (int r = 0; r < 4; ++r)
          redm[wn][wm * 32 + i * 16 + quad * 4 + r] = mt[i][r];
    }
    __syncthreads();
    float mnew[2][4], alpha[2][4];
#pragma unroll
    for (int i = 0; i < 2; ++i)
#pragma unroll
      for (int r = 0; r < 4; ++r) {
        float other = redm[1 - wn][wm * 32 + i * 16 + quad * 4 + r];
        float mn = fmaxf(fmaxf(mt[i][r], other), m_run[i][r]);
        alpha[i][r] = __expf(m_run[i][r] - mn);
        mnew[i][r] = mn;
      }
    float ssum[2][4];
#pragma unroll
    for (int i = 0; i < 2; ++i)
#pragma unroll
      for (int r = 0; r < 4; ++r) {
        float sum = 0.f;
#pragma unroll
        for (int j = 0; j < 4; ++j) {
          float p = __expf(s[i][j][r] - mnew[i][r]);
          s[i][j][r] = p;
          sum += p;
        }
#pragma unroll
        for (int off = 1; off < 16; off <<= 1) sum += __shfl_xor(sum, off);
        ssum[i][r] = sum;
      }
    if (l16 == 0) {
#pragma unroll
      for (int i = 0; i < 2; ++i)
#pragma unroll
        for (int r = 0; r < 4; ++r)
          reds[wn][wm * 32 + i * 16 + quad * 4 + r] = ssum[i][r];
    }
    // write P tile (C-layout regs -> A-operand layout in LDS)
#pragma unroll
    for (int i = 0; i < 2; ++i)
#pragma unroll
      for (int j = 0; j < 4; ++j)
#pragma unroll
        for (int r = 0; r < 4; ++r)
          Up[wm * 32 + i * 16 + quad * 4 + r][wn * 64 + j * 16 + l16] =
              f2bf(s[i][j][r]);
    __syncthreads();
#pragma unroll
    for (int i = 0; i < 2; ++i)
#pragma unroll
      for (int r = 0; r < 4; ++r) {
        float tot =
            ssum[i][r] + reds[1 - wn][wm * 32 + i * 16 + quad * 4 + r];
        l_run[i][r] = l_run[i][r] * alpha[i][r] + tot;
        m_run[i][r] = mnew[i][r];
      }
#pragma unroll
    for (int i = 0; i < 2; ++i)
#pragma unroll
      for (int j = 0; j < 4; ++j)
#pragma unroll
        for (int r = 0; r < 4; ++r) oacc[i][j][r] *= alpha[i][r];

    // ---- PV: O += P @ V_tile ----
#pragma unroll
    for (int it = 0; it < 8; ++it) {
      int idx = tid + it * 256;
      int r = idx >> 4, c = idx & 15;
      *(uint4*)&Ub[r][c * 8] =
          *(const uint4*)(vT + ((size_t)b * 128 + r) * 512 + k0 + c * 8);
    }
    __syncthreads();
#pragma unroll
    for (int kk = 0; kk < 4; ++kk) {
      short8 pa[2], vb[4];
#pragma unroll
      for (int i = 0; i < 2; ++i)
        pa[i] = *(const short8*)&Up[wm * 32 + i * 16 + l16][kk * 32 + quad * 8];
#pragma unroll
      for (int j = 0; j < 4; ++j)
        vb[j] = *(const short8*)&Ub[wn * 64 + j * 16 + l16][kk * 32 + quad * 8];
#pragma unroll
      for (int i = 0; i < 2; ++i)
#pragma unroll
        for (int j = 0; j < 4; ++j)
          oacc[i][j] = __builtin_amdgcn_mfma_f32_16x16x32_bf16(pa[i], vb[j],
                                                               oacc[i][j], 0, 0, 0);
    }
  }

  // epilogue: normalize by l, store bf16
  float invl[2][4];
#pragma unroll
  for (int i = 0; i < 2; ++i)
#pragma unroll
    for (int r = 0; r < 4; ++r) invl[i][r] = 1.0f / l_run[i][r];
#pragma unroll
  for (int i = 0; i < 2; ++i) {
    const size_t rowb = tokA + wm * 32 + i * 16 + quad * 4;
#pragma unroll
    for (int j = 0; j < 4; ++j) {
      const int col = wn * 64 + j * 16 + l16;
#pragma unroll
      for (int r = 0; r < 4; ++r)
        agg[(rowb + r) * 128 + col] = f2bf(oacc[i][j][r] * invl[i][r]);
    }
  }
}

// ---------------- merged heads: logits + value ----------------
__global__ __launch_bounds__(256) void heads_kernel(
    const unsigned short* __restrict__ x, const float* __restrict__ Wa,
    const float* __restrict__ ba, const float* __restrict__ Wcr,
    const float* __restrict__ bcr, float* __restrict__ logits,
    float* __restrict__ value) {
  __shared__ float xs[16][264];
  __shared__ float was[4096];
  __shared__ float wcs[256];
  int tid = threadIdx.x;
  size_t t0 = (size_t)blockIdx.x * 16;
  if (tid < 64) *(float4*)&wcs[tid * 4] = *(const float4*)(Wcr + tid * 4);
#pragma unroll
  for (int i = 0; i < 4; ++i) {
    int idx = tid + i * 256;  // 0..1023
    int row = idx >> 6, c4 = (idx & 63) * 4;
    uint2 u = *(const uint2*)(x + (t0 + row) * 256 + c4);
    xs[row][c4 + 0] = bf2f((unsigned short)(u.x & 0xFFFF));
    xs[row][c4 + 1] = bf2f((unsigned short)(u.x >> 16));
    xs[row][c4 + 2] = bf2f((unsigned short)(u.y & 0xFFFF));
    xs[row][c4 + 3] = bf2f((unsigned short)(u.y >> 16));
    *(float4*)&was[idx * 4] = *(const float4*)(Wa + idx * 4);
  }
  __syncthreads();
  int o = tid & 15, tl = tid >> 4;
  float accv = ba[o];
  float vacc = 0.f;
#pragma unroll 8
  for (int k2 = 0; k2 < 256; ++k2)
    accv = fmaf(xs[tl][k2], was[k2 * 16 + o], accv);
#pragma unroll
  for (int sIdx = 0; sIdx < 16; ++sIdx) {
    int k = o + sIdx * 16;
    vacc = fmaf(xs[tl][k], wcs[k], vacc);
  }
  logits[(t0 + tl) * 16 + o] = accv;
#pragma unroll
  for (int off = 1; off < 16; off <<= 1) vacc += __shfl_xor(vacc, off);
  if (o == 0) value[t0 + tl] = vacc + bcr[0];
}

// ---------------------------------------------------------------------------
extern "C" void kernel_launch(void* const* d_in, const int* in_sizes, int n_in,
                              void* d_out, int out_size, void* d_ws,
                              size_t ws_size, hipStream_t stream) {
  const float* obs = (const float*)d_in[0];
  const float* We = (const float*)d_in[2];
  const float* be = (const float*)d_in[3];
  const float* Wc = (const float*)d_in[4];
  const float* bc = (const float*)d_in[5];
  const float* Wn = (const float*)d_in[6];
  const float* bn = (const float*)d_in[7];
  const float* Wb = (const float*)d_in[8];
  const float* bb = (const float*)d_in[9];
  const float* Wi = (const float*)d_in[10];
  const float* bi = (const float*)d_in[11];
  const float* Wq = (const float*)d_in[12];
  const float* bq = (const float*)d_in[13];
  const float* Wk = (const float*)d_in[14];
  const float* bk = (const float*)d_in[15];
  const float* Wv = (const float*)d_in[16];
  const float* bv = (const float*)d_in[17];
  const float* Wp = (const float*)d_in[18];
  const float* bp = (const float*)d_in[19];
  const float* Wa = (const float*)d_in[20];
  const float* ba = (const float*)d_in[21];
  const float* Wcr = (const float*)d_in[22];
  const float* bcr = (const float*)d_in[23];

  char* base = (char*)d_ws;
  unsigned short* enc_bf = (unsigned short*)(base);              // 16.78 MB
  unsigned short* As     = (unsigned short*)(base + 16777216);   // 16.78 MB
  unsigned short* Bs     = (unsigned short*)(base + 33554432);   // 16.78 MB
  unsigned short* obsagg = (unsigned short*)(base + 50331648);   // 8.39 MB (obs_bf -> agg)
  unsigned short* msgx   = (unsigned short*)(base + 58720256);   // 16.78 MB (msg -> x)
  unsigned short* msg_bf = msgx;
  unsigned short* x_bf   = msgx;
  unsigned short* vT     = (unsigned short*)(base + 75497472);   // 8.39 MB
  float* impA            = (float*)(base + 83886080);
  float* impB            = (float*)(base + 84017152);
  unsigned short* WeT    = (unsigned short*)(base + 84148224);   // 64 KB
  unsigned short* Wmq    = (unsigned short*)(base + 84213760);   // 128 KB
  unsigned short* Wkv    = (unsigned short*)(base + 84344832);   // 64 KB
  unsigned short* WpT    = (unsigned short*)(base + 84410368);   // 192 KB
  float* bmb             = (float*)(base + 84606976);            // 512 B

  prep_w<<<897, 256, 0, stream>>>(We, Wq, Wk, Wv, Wp, Wc, Wn, Wb, bc, bn, bb,
                                  WeT, Wmq, Wkv, WpT, bmb);
  prep_obs<<<8192, 256, 0, stream>>>(obs, obsagg, As, Bs);

  // enc = relu(obs @ We + be)
  gemm_dual<1, 1><<<dim3(2, 512), 256, 0, stream>>>(
      obsagg, 128, 128, nullptr, 0, 128, WeT, 128, be, be, nullptr, enc_bf,
      256, enc_bf, 256, 256);
  imp_kernel<<<8192, 256, 0, stream>>>(enc_bf, Wi, bi, impA, impB);

  // msg | q(scaled into As)
  gemm_dual<0, 2><<<dim3(2, 512), 256, 0, stream>>>(
      enc_bf, 256, 256, nullptr, 0, 256, Wmq, 256, bmb, bq, impA, msg_bf, 128,
      As, 256, 128);
  // k(scaled into Bs) | v(transposed into vT)
  gemm_dual<2, 3><<<dim3(2, 512), 256, 0, stream>>>(
      msg_bf, 128, 128, nullptr, 0, 128, Wkv, 128, bk, bv, impB, Bs, 256, vT,
      0, 128);

  // fused attention -> agg
  flash_attn<<<dim3(8, 64), 256, 0, stream>>>(As, Bs, vT, obsagg);

  // x = relu([enc | agg] @ Wp + bp)
  gemm_dual<1, 1><<<dim3(2, 512), 256, 0, stream>>>(
      enc_bf, 256, 256, obsagg, 128, 384, WpT, 384, bp, bp, nullptr, x_bf, 256,
      x_bf, 256, 256);

  heads_kernel<<<2048, 256, 0, stream>>>(x_bf, Wa, ba, Wcr, bcr,
                                         (float*)d_out, (float*)d_out + 524288);
}

// Round 4
// 223.249 us; speedup vs baseline: 2.6263x; 1.1158x over previous
//
#include <hip/hip_runtime.h>
#include <math.h>

// ---------------------------------------------------------------------------
// HADCommNetwork forward, bf16-MFMA, flash v2 (single-pass softmax) + fused
// heads. B=64, N=512, OBS=128, H=256, M=128, ACT=16, T=32768.
// 8 launches: prep_w | prep_obs | enc | imp | msg|q | k|v | flash2 | x+heads
// ---------------------------------------------------------------------------

typedef __attribute__((ext_vector_type(8))) short short8;
typedef __attribute__((ext_vector_type(4))) float f32x4;

#define RSQRT_D 0.08838834764831843f  // 1/sqrt(128)

__device__ __forceinline__ unsigned short f2bf(float f) {
  union { float f; unsigned u; } v; v.f = f;
  return (unsigned short)((v.u + 0x7FFFu + ((v.u >> 16) & 1u)) >> 16);
}
__device__ __forceinline__ float bf2f(unsigned short h) {
  union { unsigned u; float f; } v; v.u = ((unsigned)h) << 16;
  return v.f;
}
__device__ __forceinline__ unsigned pack2(float a, float b) {
  return (unsigned)f2bf(a) | ((unsigned)f2bf(b) << 16);
}

// XOR-swizzled LDS index: stride 128 shorts, chunk (16B) swizzled by row.
__device__ __forceinline__ int swz(int row, int chunk) {
  return row * 128 + ((chunk ^ ((row & 7) << 1)) << 3);
}

// ---------------- consolidated weight prep ----------------
__global__ __launch_bounds__(256) void prep_w(
    const float* __restrict__ We, const float* __restrict__ Wq,
    const float* __restrict__ Wk, const float* __restrict__ Wv,
    const float* __restrict__ Wp, const float* __restrict__ Wc,
    const float* __restrict__ Wn, const float* __restrict__ Wb,
    const float* __restrict__ bc, const float* __restrict__ bn,
    const float* __restrict__ bb, const float* __restrict__ Wa,
    const float* __restrict__ Wcr, unsigned short* __restrict__ WeT,
    unsigned short* __restrict__ Wmq, unsigned short* __restrict__ Wkv,
    unsigned short* __restrict__ WpT, unsigned short* __restrict__ WaCrT,
    float* __restrict__ bm) {
  int idx = blockIdx.x * 256 + threadIdx.x;
  if (idx < 32768) {                 // WeT[n 256][k 128]
    int n = idx >> 7, k = idx & 127;
    WeT[idx] = f2bf(We[k * 256 + n]);
  } else if (idx < 65536) {          // Wmq rows 0..127: WmT[d 128][h 256]
    int i = idx - 32768;
    int d = i >> 8, h = i & 255;
    float v = (d < 32)   ? Wc[h * 32 + d]
            : (d < 96)   ? Wn[h * 64 + (d - 32)]
                         : Wb[h * 32 + (d - 96)];
    Wmq[i] = f2bf(v);
  } else if (idx < 98304) {          // Wmq rows 128..255: WqT[n 128][k 256]
    int i = idx - 65536;
    int n = i >> 8, k = i & 255;
    Wmq[32768 + i] = f2bf(Wq[k * 128 + n]);
  } else if (idx < 114688) {         // Wkv rows 0..127: WkT[128][128]
    int i = idx - 98304;
    int n = i >> 7, k = i & 127;
    Wkv[i] = f2bf(Wk[k * 128 + n]);
  } else if (idx < 131072) {         // Wkv rows 128..255: WvT[128][128]
    int i = idx - 114688;
    int n = i >> 7, k = i & 127;
    Wkv[16384 + i] = f2bf(Wv[k * 128 + n]);
  } else if (idx < 229376) {         // WpT[n 256][k 384]
    int i = idx - 131072;
    int n = i / 384, k = i - n * 384;
    WpT[i] = f2bf(Wp[k * 256 + n]);
  } else if (idx < 237568) {         // WaCrT[32][256]: 0..15 Wa^T, 16 Wcr^T
    int i = idx - 229376;
    int n = i >> 8, k = i & 255;
    float v = (n < 16) ? Wa[k * 16 + n] : (n == 16) ? Wcr[k] : 0.f;
    WaCrT[i] = f2bf(v);
  } else if (idx < 237696) {         // bm
    int i = idx - 237568;
    bm[i] = (i < 32) ? bc[i] : (i < 96) ? bn[i - 32] : bb[i - 96];
  }
}

// ---------------- obs prep: norms + bf16 conversions ----------------
__global__ __launch_bounds__(256) void prep_obs(
    const float* __restrict__ obs, unsigned short* __restrict__ obs_bf,
    unsigned short* __restrict__ As, unsigned short* __restrict__ Bs) {
  int t = blockIdx.x * 4 + (threadIdx.x >> 6);
  int lane = threadIdx.x & 63;
  const float* row = obs + (size_t)t * 128;
  float2 o = *(const float2*)(row + lane * 2);
  float s2 = o.x * o.x + o.y * o.y;
#pragma unroll
  for (int off = 1; off < 64; off <<= 1) s2 += __shfl_xor(s2, off);
  float inv = 1.f / (sqrtf(s2) + 1e-8f);
  ((unsigned*)obs_bf)[(size_t)t * 64 + lane] = pack2(o.x, o.y);
  ((unsigned*)As)[(size_t)t * 128 + 64 + lane] =
      pack2(o.x * 0.5f * inv, o.y * 0.5f * inv);
  ((unsigned*)Bs)[(size_t)t * 128 + 64 + lane] = pack2(o.x * inv, o.y * inv);
}

// ---------------- importance ----------------
__global__ __launch_bounds__(256) void imp_kernel(
    const unsigned short* __restrict__ enc, const float* __restrict__ Wi,
    const float* __restrict__ bi, float* __restrict__ impA,
    float* __restrict__ impB) {
  int t = blockIdx.x * 4 + (threadIdx.x >> 6);
  int lane = threadIdx.x & 63;
  const unsigned* eu = (const unsigned*)(enc + (size_t)t * 256);
  unsigned u0 = eu[lane * 2], u1 = eu[lane * 2 + 1];
  float4 w = *(const float4*)(Wi + lane * 4);
  float s = bf2f((unsigned short)(u0 & 0xFFFF)) * w.x +
            bf2f((unsigned short)(u0 >> 16)) * w.y +
            bf2f((unsigned short)(u1 & 0xFFFF)) * w.z +
            bf2f((unsigned short)(u1 >> 16)) * w.w;
#pragma unroll
  for (int off = 1; off < 64; off <<= 1) s += __shfl_xor(s, off);
  if (lane == 0) {
    float sg = 1.0f / (1.0f + __expf(-(s + bi[0])));
    impA[t] = sg * RSQRT_D;
    impB[t] = sg;
  }
}

// ---------------- dual-epilogue NT MFMA GEMM ----------------
// Modes: 0 = bf16(+bias), 1 = relu bf16, 2 = bf16*scale[row] (+bias),
//        3 = transposed write into vT[b][d][tok] (+bias).
template <int MODE>
__device__ __forceinline__ void epi_store(unsigned short* out, int ldc,
                                          const float* bias,
                                          const float* scale, int rowb,
                                          int col, const f32x4& a) {
  const float bv = bias ? bias[col] : 0.f;
  if constexpr (MODE == 3) {
    unsigned short t0 = f2bf(a[0] + bv), t1 = f2bf(a[1] + bv);
    unsigned short t2 = f2bf(a[2] + bv), t3 = f2bf(a[3] + bv);
    uint2 o;
    o.x = (unsigned)t0 | ((unsigned)t1 << 16);
    o.y = (unsigned)t2 | ((unsigned)t3 << 16);
    *(uint2*)(out + ((size_t)(rowb >> 9) * 128 + col) * 512 + (rowb & 511)) = o;
  } else {
#pragma unroll
    for (int r = 0; r < 4; ++r) {
      float v = a[r] + bv;
      if constexpr (MODE == 1) v = fmaxf(v, 0.f);
      if constexpr (MODE == 2) v *= scale[rowb + r];
      out[(size_t)(rowb + r) * ldc + col] = f2bf(v);
    }
  }
}

template <int M0, int M1>
__global__ __launch_bounds__(256, 2) void gemm_dual(
    const unsigned short* __restrict__ A1, int lda1, int K1,
    const unsigned short* __restrict__ A2, int lda2, int Ktot,
    const unsigned short* __restrict__ Bt, int ldb,
    const float* __restrict__ bias0, const float* __restrict__ bias1,
    const float* __restrict__ scale, unsigned short* __restrict__ out0,
    int ldc0, unsigned short* __restrict__ out1, int ldc1, int xsplit) {
  __shared__ unsigned short Asr[64][72];
  __shared__ unsigned short Bsr[128][72];
  const int tid = threadIdx.x;
  const int lane = tid & 63, wave = tid >> 6;
  const int quad = lane >> 4, l16 = lane & 15;
  const int wm = wave & 1, wn = wave >> 1;
  const int bm = blockIdx.y * 64, bn = blockIdx.x * 128;

  f32x4 acc[2][4];
#pragma unroll
  for (int i = 0; i < 2; ++i)
#pragma unroll
    for (int j = 0; j < 4; ++j) acc[i][j] = (f32x4){0.f, 0.f, 0.f, 0.f};

  const int ar = tid >> 3, ac = tid & 7;
  for (int kt = 0; kt < Ktot; kt += 64) {
    const unsigned short* Asrc;
    int lda, kloc;
    if (kt < K1) { Asrc = A1; lda = lda1; kloc = kt; }
    else         { Asrc = A2; lda = lda2; kloc = kt - K1; }
#pragma unroll
    for (int it = 0; it < 2; ++it) {
      int r = ar + it * 32;
      uint4 v = *(const uint4*)(Asrc + (size_t)(bm + r) * lda + kloc + ac * 8);
      *(uint4*)&Asr[r][ac * 8] = v;
    }
#pragma unroll
    for (int it = 0; it < 4; ++it) {
      int r = ar + it * 32;
      uint4 v = *(const uint4*)(Bt + (size_t)(bn + r) * ldb + kt + ac * 8);
      *(uint4*)&Bsr[r][ac * 8] = v;
    }
    __syncthreads();
#pragma unroll
    for (int ks = 0; ks < 64; ks += 32) {
      short8 af[2], bfr[4];
#pragma unroll
      for (int i = 0; i < 2; ++i)
        af[i] = *(const short8*)&Asr[wm * 32 + i * 16 + l16][ks + quad * 8];
#pragma unroll
      for (int j = 0; j < 4; ++j)
        bfr[j] = *(const short8*)&Bsr[wn * 64 + j * 16 + l16][ks + quad * 8];
#pragma unroll
      for (int i = 0; i < 2; ++i)
#pragma unroll
        for (int j = 0; j < 4; ++j)
          acc[i][j] = __builtin_amdgcn_mfma_f32_16x16x32_bf16(af[i], bfr[j],
                                                              acc[i][j], 0, 0, 0);
    }
    __syncthreads();
  }
  const int colb = bn + wn * 64 + l16;
#pragma unroll
  for (int i = 0; i < 2; ++i) {
    const int rowb = bm + wm * 32 + i * 16 + quad * 4;
#pragma unroll
    for (int j = 0; j < 4; ++j) {
      const int col = colb + j * 16;
      if (col < xsplit)
        epi_store<M0>(out0, ldc0, bias0, scale, rowb, col, acc[i][j]);
      else
        epi_store<M1>(out1, ldc1, bias1, scale, rowb, col - xsplit, acc[i][j]);
    }
  }
}

// ---------------- flash v2: single-pass softmax ----------------
// 1024 blocks: b = id&63 (XCD-local batches), qt = id>>6 (Q-tile 32).
// All 512 keys' S held in regs (s[4][4] f32x4/thread); exact softmax; P->LDS
// per 128-key chunk; PV MFMA vs vT chunks.
__global__ __launch_bounds__(256, 3) void flash2(
    const unsigned short* __restrict__ As, const unsigned short* __restrict__ Bs,
    const unsigned short* __restrict__ vT, unsigned short* __restrict__ agg) {
  __shared__ unsigned short Ub[128 * 128];  // 32 KB, swizzled
  __shared__ unsigned short Pp[32 * 128];   // 8 KB, swizzled
  __shared__ float redm[2][32];
  __shared__ float reds[2][32];
  const int tid = threadIdx.x;
  const int lane = tid & 63, wave = tid >> 6;
  const int quad = lane >> 4, l16 = lane & 15;
  const int wm = wave & 1, wn = wave >> 1;
  const int b = blockIdx.x & 63;
  const int qt = blockIdx.x >> 6;
  const size_t tokA = (size_t)b * 512 + qt * 32;

  // A fragments: rows wm*16 + l16 (32 q-rows), K=256
  short8 af[8];
#pragma unroll
  for (int kc = 0; kc < 8; ++kc)
    af[kc] = *(const short8*)(As + (tokA + wm * 16 + l16) * 256 + kc * 32 +
                              quad * 8);

  f32x4 s[4][4];  // [key-tile kt][n-tile nt]
#pragma unroll
  for (int kt = 0; kt < 4; ++kt)
#pragma unroll
    for (int nt = 0; nt < 4; ++nt) s[kt][nt] = (f32x4){0.f, 0.f, 0.f, 0.f};

  const int lr = tid >> 4, lc = tid & 15;  // staging: 16 rows/iter over 8 iters

  // ---- QK^T: all 512 keys ----
#pragma unroll
  for (int kt = 0; kt < 4; ++kt) {
#pragma unroll
    for (int kh = 0; kh < 2; ++kh) {
      __syncthreads();
#pragma unroll
      for (int it = 0; it < 8; ++it) {
        int r = lr + it * 16;
        *(uint4*)&Ub[swz(r, lc)] =
            *(const uint4*)(Bs + ((size_t)b * 512 + kt * 128 + r) * 256 +
                            kh * 128 + lc * 8);
      }
      __syncthreads();
#pragma unroll
      for (int kk = 0; kk < 4; ++kk) {
        short8 bfr[4];
#pragma unroll
        for (int nt = 0; nt < 4; ++nt) {
          int rrow = wn * 64 + nt * 16 + l16;
          bfr[nt] = *(const short8*)&Ub[swz(rrow, kk * 4 + quad)];
        }
#pragma unroll
        for (int nt = 0; nt < 4; ++nt)
          s[kt][nt] = __builtin_amdgcn_mfma_f32_16x16x32_bf16(
              af[kh * 4 + kk], bfr[nt], s[kt][nt], 0, 0, 0);
      }
    }
  }

  // ---- exact softmax (rows = wm*16 + quad*4 + r) ----
  const int rbase = wm * 16 + quad * 4;
  float mt4[4];
#pragma unroll
  for (int r = 0; r < 4; ++r) {
    float mv = -1e30f;
#pragma unroll
    for (int kt = 0; kt < 4; ++kt)
#pragma unroll
      for (int nt = 0; nt < 4; ++nt) mv = fmaxf(mv, s[kt][nt][r]);
#pragma unroll
    for (int off = 1; off < 16; off <<= 1) mv = fmaxf(mv, __shfl_xor(mv, off));
    mt4[r] = mv;
  }
  if (l16 == 0) {
#pragma unroll
    for (int r = 0; r < 4; ++r) redm[wn][rbase + r] = mt4[r];
  }
  __syncthreads();
  float lsum[4];
#pragma unroll
  for (int r = 0; r < 4; ++r) {
    float mfull = fmaxf(mt4[r], redm[1 ^ wn][rbase + r]);
    float sum = 0.f;
#pragma unroll
    for (int kt = 0; kt < 4; ++kt)
#pragma unroll
      for (int nt = 0; nt < 4; ++nt) {
        float p = __expf(s[kt][nt][r] - mfull);
        s[kt][nt][r] = p;
        sum += p;
      }
#pragma unroll
    for (int off = 1; off < 16; off <<= 1) sum += __shfl_xor(sum, off);
    lsum[r] = sum;
  }
  if (l16 == 0) {
#pragma unroll
    for (int r = 0; r < 4; ++r) reds[wn][rbase + r] = lsum[r];
  }
  __syncthreads();
  float linv[4];
#pragma unroll
  for (int r = 0; r < 4; ++r)
    linv[r] = 1.0f / (lsum[r] + reds[1 ^ wn][rbase + r]);

  // ---- PV over 4 key chunks ----
  f32x4 oacc[4];
#pragma unroll
  for (int nt = 0; nt < 4; ++nt) oacc[nt] = (f32x4){0.f, 0.f, 0.f, 0.f};
#pragma unroll
  for (int vt = 0; vt < 4; ++vt) {
    __syncthreads();
    // P chunk -> LDS (A-operand layout)
#pragma unroll
    for (int nt = 0; nt < 4; ++nt)
#pragma unroll
      for (int r = 0; r < 4; ++r) {
        int row = rbase + r;
        int col = wn * 64 + nt * 16 + l16;
        Pp[row * 128 + (((col >> 3) ^ ((row & 7) << 1)) << 3) + (col & 7)] =
            f2bf(s[vt][nt][r]);
      }
    // V chunk: Ub[d][k]
#pragma unroll
    for (int it = 0; it < 8; ++it) {
      int r = lr + it * 16;
      *(uint4*)&Ub[swz(r, lc)] =
          *(const uint4*)(vT + ((size_t)b * 128 + r) * 512 + vt * 128 + lc * 8);
    }
    __syncthreads();
#pragma unroll
    for (int kk = 0; kk < 4; ++kk) {
      short8 pa = *(const short8*)&Pp[swz(wm * 16 + l16, kk * 4 + quad)];
#pragma unroll
      for (int nt = 0; nt < 4; ++nt) {
        int rrow = wn * 64 + nt * 16 + l16;
        short8 vb = *(const short8*)&Ub[swz(rrow, kk * 4 + quad)];
        oacc[nt] = __builtin_amdgcn_mfma_f32_16x16x32_bf16(pa, vb, oacc[nt],
                                                           0, 0, 0);
      }
    }
  }

  // epilogue
#pragma unroll
  for (int nt = 0; nt < 4; ++nt) {
    const int col = wn * 64 + nt * 16 + l16;
#pragma unroll
    for (int r = 0; r < 4; ++r)
      agg[(tokA + rbase + r) * 128 + col] = f2bf(oacc[nt][r] * linv[r]);
  }
}

// ---------------- fused x-GEMM + heads ----------------
// x = relu([enc|agg] @ WpT^T + bp) (32x256 tile, kept in LDS), then
// logits/value via MFMA vs WaCrT[32][256]. 1024 blocks of 32 tokens.
__global__ __launch_bounds__(256, 3) void xh_gemm(
    const unsigned short* __restrict__ A1, const unsigned short* __restrict__ A2,
    const unsigned short* __restrict__ WpT, const float* __restrict__ bp,
    const unsigned short* __restrict__ WaCrT, const float* __restrict__ ba,
    const float* __restrict__ bcr, float* __restrict__ logits,
    float* __restrict__ value) {
  __shared__ unsigned short Asr[32][72];
  __shared__ unsigned short Bsr[256][72];  // aliased as xs[32][264] later
  const int tid = threadIdx.x;
  const int lane = tid & 63, wave = tid >> 6;
  const int quad = lane >> 4, l16 = lane & 15;
  const int bm = blockIdx.x * 32;

  f32x4 acc[2][4];
#pragma unroll
  for (int i = 0; i < 2; ++i)
#pragma unroll
    for (int j = 0; j < 4; ++j) acc[i][j] = (f32x4){0.f, 0.f, 0.f, 0.f};

  const int ar = tid >> 3, ac = tid & 7;
  for (int kt = 0; kt < 384; kt += 64) {
    const unsigned short* Asrc;
    int lda, kloc;
    if (kt < 256) { Asrc = A1; lda = 256; kloc = kt; }
    else          { Asrc = A2; lda = 128; kloc = kt - 256; }
    *(uint4*)&Asr[ar][ac * 8] =
        *(const uint4*)(Asrc + (size_t)(bm + ar) * lda + kloc + ac * 8);
#pragma unroll
    for (int it = 0; it < 8; ++it) {
      int idx = tid + it * 256;
      int r = idx >> 3, c = idx & 7;
      *(uint4*)&Bsr[r][c * 8] = *(const uint4*)(WpT + (size_t)r * 384 + kt + c * 8);
    }
    __syncthreads();
#pragma unroll
    for (int kk = 0; kk < 2; ++kk) {
      short8 afr[2], bfr[4];
#pragma unroll
      for (int i = 0; i < 2; ++i)
        afr[i] = *(const short8*)&Asr[i * 16 + l16][kk * 32 + quad * 8];
#pragma unroll
      for (int j = 0; j < 4; ++j)
        bfr[j] = *(const short8*)&Bsr[wave * 64 + j * 16 + l16][kk * 32 + quad * 8];
#pragma unroll
      for (int i = 0; i < 2; ++i)
#pragma unroll
        for (int j = 0; j < 4; ++j)
          acc[i][j] = __builtin_amdgcn_mfma_f32_16x16x32_bf16(afr[i], bfr[j],
                                                              acc[i][j], 0, 0, 0);
    }
    __syncthreads();
  }
  // write x tile (relu, bf16) into LDS aliased over Bsr
  unsigned short* xs = &Bsr[0][0];  // [32][264]
#pragma unroll
  for (int i = 0; i < 2; ++i) {
    const int row = i * 16 + quad * 4;
#pragma unroll
    for (int j = 0; j < 4; ++j) {
      const int col = wave * 64 + j * 16 + l16;
      const float bv = bp[col];
#pragma unroll
      for (int r = 0; r < 4; ++r)
        xs[(row + r) * 264 + col] = f2bf(fmaxf(acc[i][j][r] + bv, 0.f));
    }
  }
  __syncthreads();
  // heads: 32x32 out tile; wave quadrant (wm2 rows, wn2 cols)
  const int wm2 = wave & 1, wn2 = wave >> 1;
  f32x4 hacc = (f32x4){0.f, 0.f, 0.f, 0.f};
#pragma unroll
  for (int kk = 0; kk < 8; ++kk) {
    short8 pa = *(const short8*)&xs[(wm2 * 16 + l16) * 264 + kk * 32 + quad * 8];
    short8 wb = *(const short8*)(WaCrT + (size_t)(wn2 * 16 + l16) * 256 +
                                 kk * 32 + quad * 8);
    hacc = __builtin_amdgcn_mfma_f32_16x16x32_bf16(pa, wb, hacc, 0, 0, 0);
  }
  const int n = wn2 * 16 + l16;
#pragma unroll
  for (int r = 0; r < 4; ++r) {
    const size_t tok = bm + wm2 * 16 + quad * 4 + r;
    if (n < 16)
      logits[tok * 16 + n] = hacc[r] + ba[n];
    else if (n == 16)
      value[tok] = hacc[r] + bcr[0];
  }
}

// ---------------------------------------------------------------------------
extern "C" void kernel_launch(void* const* d_in, const int* in_sizes, int n_in,
                              void* d_out, int out_size, void* d_ws,
                              size_t ws_size, hipStream_t stream) {
  const float* obs = (const float*)d_in[0];
  const float* We = (const float*)d_in[2];
  const float* be = (const float*)d_in[3];
  const float* Wc = (const float*)d_in[4];
  const float* bc = (const float*)d_in[5];
  const float* Wn = (const float*)d_in[6];
  const float* bn = (const float*)d_in[7];
  const float* Wb = (const float*)d_in[8];
  const float* bb = (const float*)d_in[9];
  const float* Wi = (const float*)d_in[10];
  const float* bi = (const float*)d_in[11];
  const float* Wq = (const float*)d_in[12];
  const float* bq = (const float*)d_in[13];
  const float* Wk = (const float*)d_in[14];
  const float* bk = (const float*)d_in[15];
  const float* Wv = (const float*)d_in[16];
  const float* bv = (const float*)d_in[17];
  const float* Wp = (const float*)d_in[18];
  const float* bp = (const float*)d_in[19];
  const float* Wa = (const float*)d_in[20];
  const float* ba = (const float*)d_in[21];
  const float* Wcr = (const float*)d_in[22];
  const float* bcr = (const float*)d_in[23];

  char* base = (char*)d_ws;
  unsigned short* enc_bf = (unsigned short*)(base);              // 16.78 MB
  unsigned short* As     = (unsigned short*)(base + 16777216);   // 16.78 MB
  unsigned short* Bs     = (unsigned short*)(base + 33554432);   // 16.78 MB
  unsigned short* obsagg = (unsigned short*)(base + 50331648);   // 8.39 MB (obs_bf -> agg)
  unsigned short* msg_bf = (unsigned short*)(base + 58720256);   // 8.39 MB
  unsigned short* vT     = (unsigned short*)(base + 75497472);   // 8.39 MB
  float* impA            = (float*)(base + 83886080);
  float* impB            = (float*)(base + 84017152);
  unsigned short* WeT    = (unsigned short*)(base + 84148224);   // 64 KB
  unsigned short* Wmq    = (unsigned short*)(base + 84213760);   // 128 KB
  unsigned short* Wkv    = (unsigned short*)(base + 84344832);   // 64 KB
  unsigned short* WpT    = (unsigned short*)(base + 84410368);   // 192 KB
  float* bmb             = (float*)(base + 84606976);            // 512 B
  unsigned short* WaCrT  = (unsigned short*)(base + 84607488);   // 16 KB

  prep_w<<<929, 256, 0, stream>>>(We, Wq, Wk, Wv, Wp, Wc, Wn, Wb, bc, bn, bb,
                                  Wa, Wcr, WeT, Wmq, Wkv, WpT, WaCrT, bmb);
  prep_obs<<<8192, 256, 0, stream>>>(obs, obsagg, As, Bs);

  // enc = relu(obs @ We + be)
  gemm_dual<1, 1><<<dim3(2, 512), 256, 0, stream>>>(
      obsagg, 128, 128, nullptr, 0, 128, WeT, 128, be, be, nullptr, enc_bf,
      256, enc_bf, 256, 256);
  imp_kernel<<<8192, 256, 0, stream>>>(enc_bf, Wi, bi, impA, impB);

  // msg | q(scaled into As)
  gemm_dual<0, 2><<<dim3(2, 512), 256, 0, stream>>>(
      enc_bf, 256, 256, nullptr, 0, 256, Wmq, 256, bmb, bq, impA, msg_bf, 128,
      As, 256, 128);
  // k(scaled into Bs) | v(transposed into vT)
  gemm_dual<2, 3><<<dim3(2, 512), 256, 0, stream>>>(
      msg_bf, 128, 128, nullptr, 0, 128, Wkv, 128, bk, bv, impB, Bs, 256, vT,
      0, 128);

  // fused attention -> agg
  flash2<<<1024, 256, 0, stream>>>(As, Bs, vT, obsagg);

  // x = relu([enc | agg] @ Wp + bp) fused with logits/value heads
  xh_gemm<<<1024, 256, 0, stream>>>(enc_bf, obsagg, WpT, bp, WaCrT, ba, bcr,
                                    (float*)d_out, (float*)d_out + 524288);
}